// Round 1
// baseline (369.165 us; speedup 1.0000x reference)
//
#include <hip/hip_runtime.h>
#include <stdint.h>

// ROISelect: B=128 batches, N=131072 anchors, K=256 top-k + ROI gather.
// Strategy: single HBM pass. Stage1: per-(batch,split) block keeps its 16K
// chunk in registers, LDS-histograms order-preserving uint32, finds local
// top-256 bucket threshold, compacts candidate keys (value<<32 | N-1-idx) to
// global scratch. Stage2: per-batch block selects/sorts global top-256 from
// ~2.7K candidates via LDS histogram + bitonic sort, gathers ROI rows.

#define BATCH   128
#define NANCH   131072
#define KSEL    256
#define SPLITS  8
#define CHUNK   (NANCH / SPLITS)     // 16384
#define TPB     256
#define V4PT    (CHUNK / TPB / 4)    // 16 float4 per thread (64 floats)
#define NBUCK   4096
#define CAPMAX  8192                 // per-batch candidate capacity (keys)
#define SORTCAP 2048

typedef unsigned long long ull;

__device__ __forceinline__ unsigned ord_of(float f) {
    unsigned u = __float_as_uint(f);
    // monotone map: larger float -> larger uint
    return (u & 0x80000000u) ? ~u : (u | 0x80000000u);
}
__device__ __forceinline__ float f_of_ord(unsigned o) {
    unsigned u = (o & 0x80000000u) ? (o ^ 0x80000000u) : ~o;
    return __uint_as_float(u);
}

// ---------------------------------------------------------------- stage 1
__global__ __launch_bounds__(TPB) void topk_stage1(
    const float* __restrict__ score, ull* __restrict__ cand,
    int* __restrict__ cnt, int cap)
{
    __shared__ int hist[NBUCK];
    __shared__ int scan[TPB];
    __shared__ int s_bstar;
    __shared__ int s_base;

    const int t  = threadIdx.x;
    const int sp = blockIdx.x;   // split within batch row
    const int b  = blockIdx.y;   // batch

    // coalesced float4 loads; whole chunk lives in registers (64 VGPRs)
    const float4* src = (const float4*)(score + (size_t)b * NANCH + (size_t)sp * CHUNK);
    float4 v[V4PT];
#pragma unroll
    for (int i = 0; i < V4PT; ++i) v[i] = src[i * TPB + t];

    for (int i = t; i < NBUCK; i += TPB) hist[i] = 0;
    __syncthreads();

#pragma unroll
    for (int i = 0; i < V4PT; ++i) {
        atomicAdd(&hist[ord_of(v[i].x) >> 20], 1);
        atomicAdd(&hist[ord_of(v[i].y) >> 20], 1);
        atomicAdd(&hist[ord_of(v[i].z) >> 20], 1);
        atomicAdd(&hist[ord_of(v[i].w) >> 20], 1);
    }
    __syncthreads();

    // per-thread partial over its 16-bucket group, then inclusive suffix scan
    int ps = 0;
#pragma unroll
    for (int p = 0; p < 16; ++p) ps += hist[t * 16 + p];
    scan[t] = ps;
    __syncthreads();
    for (int off = 1; off < TPB; off <<= 1) {
        int add = (t + off < TPB) ? scan[t + off] : 0;
        __syncthreads();
        scan[t] += add;
        __syncthreads();
    }
    // largest bucket b* with suffix-count S(b*) >= KSEL  (unique crossing)
    {
        int running = (t + 1 < TPB) ? scan[t + 1] : 0;   // S(end of my group)
#pragma unroll
        for (int p = 15; p >= 0; --p) {
            int nr = running + hist[t * 16 + p];
            if (nr >= KSEL && running < KSEL) s_bstar = t * 16 + p;
            running = nr;
        }
    }
    __syncthreads();
    const unsigned thr = (unsigned)s_bstar << 20;   // qualify iff ordered >= thr

    // count qualifiers per thread
    int qc = 0;
#pragma unroll
    for (int i = 0; i < V4PT; ++i) {
        qc += (ord_of(v[i].x) >= thr);
        qc += (ord_of(v[i].y) >= thr);
        qc += (ord_of(v[i].z) >= thr);
        qc += (ord_of(v[i].w) >= thr);
    }
    __syncthreads();           // scan[] reuse
    scan[t] = qc;
    __syncthreads();
    for (int off = 1; off < TPB; off <<= 1) {        // inclusive ascending scan
        int add = (t >= off) ? scan[t - off] : 0;
        __syncthreads();
        scan[t] += add;
        __syncthreads();
    }
    if (t == TPB - 1) s_base = atomicAdd(&cnt[b], scan[TPB - 1]);
    __syncthreads();

    int pos = s_base + scan[t] - qc;
    ull* cb = cand + (size_t)b * cap;
    const int nbase = sp * CHUNK;
#pragma unroll
    for (int i = 0; i < V4PT; ++i) {
        const int n0 = nbase + 4 * (i * TPB + t);
        unsigned o;
        o = ord_of(v[i].x);
        if (o >= thr && pos < cap) { cb[pos++] = ((ull)o << 32) | (unsigned)(NANCH - 1 - n0); }
        o = ord_of(v[i].y);
        if (o >= thr && pos < cap) { cb[pos++] = ((ull)o << 32) | (unsigned)(NANCH - 2 - n0); }
        o = ord_of(v[i].z);
        if (o >= thr && pos < cap) { cb[pos++] = ((ull)o << 32) | (unsigned)(NANCH - 3 - n0); }
        o = ord_of(v[i].w);
        if (o >= thr && pos < cap) { cb[pos++] = ((ull)o << 32) | (unsigned)(NANCH - 4 - n0); }
    }
}

// ---------------------------------------------------------------- stage 2
__global__ __launch_bounds__(TPB) void topk_stage2(
    const ull* __restrict__ cand, const int* __restrict__ cnt,
    const float* __restrict__ roi, float* __restrict__ out_roi,
    float* __restrict__ out_score, int cap)
{
    __shared__ int hist[NBUCK];
    __shared__ int scan[TPB];
    __shared__ ull buf[SORTCAP];
    __shared__ int s_bstar, s_csel;

    const int t = threadIdx.x;
    const int b = blockIdx.x;
    const int c = min(cnt[b], cap);
    const ull* cb = cand + (size_t)b * cap;

    for (int i = t; i < NBUCK; i += TPB) hist[i] = 0;
    if (t == 0) s_csel = 0;
    __syncthreads();
    for (int i = t; i < c; i += TPB) atomicAdd(&hist[(unsigned)(cb[i] >> 52)], 1);
    __syncthreads();

    int ps = 0;
#pragma unroll
    for (int p = 0; p < 16; ++p) ps += hist[t * 16 + p];
    scan[t] = ps;
    __syncthreads();
    for (int off = 1; off < TPB; off <<= 1) {
        int add = (t + off < TPB) ? scan[t + off] : 0;
        __syncthreads();
        scan[t] += add;
        __syncthreads();
    }
    {
        int running = (t + 1 < TPB) ? scan[t + 1] : 0;
#pragma unroll
        for (int p = 15; p >= 0; --p) {
            int nr = running + hist[t * 16 + p];
            if (nr >= KSEL && running < KSEL) s_bstar = t * 16 + p;
            running = nr;
        }
    }
    __syncthreads();
    const unsigned bstar = (unsigned)s_bstar;

    // compact survivors (bucket >= b*) into LDS; count C in [256, ~500]
    for (int i = t; i < c; i += TPB) {
        ull k = cb[i];
        if ((unsigned)(k >> 52) >= bstar) {
            int p = atomicAdd(&s_csel, 1);
            if (p < SORTCAP) buf[p] = k;
        }
    }
    __syncthreads();
    const int C = min(s_csel, SORTCAP);
    int P = KSEL;
    while (P < C) P <<= 1;                 // pow2 in [256, 2048]
    for (int i = C + t; i < P; i += TPB) buf[i] = 0;   // pad (sinks in desc sort)
    __syncthreads();

    // bitonic sort descending on uint64 keys
    for (int kk = 2; kk <= P; kk <<= 1) {
        for (int j = kk >> 1; j > 0; j >>= 1) {
            for (int i = t; i < P; i += TPB) {
                int ixj = i ^ j;
                if (ixj > i) {
                    ull a = buf[i], d = buf[ixj];
                    bool up = (i & kk) == 0;
                    bool sw = up ? (a < d) : (a > d);
                    if (sw) { buf[i] = d; buf[ixj] = a; }
                }
            }
            __syncthreads();
        }
    }

    // emit: sorted scores + gathered ROI rows
    ull k = buf[t];
    unsigned o = (unsigned)(k >> 32);
    int idx = NANCH - 1 - (int)(unsigned)(k & 0xffffffffull);
    out_score[b * KSEL + t] = f_of_ord(o);
    float4 r = ((const float4*)roi)[(size_t)b * NANCH + idx];
    ((float4*)out_roi)[b * KSEL + t] = r;
}

// ---------------------------------------------------------------- launch
extern "C" void kernel_launch(void* const* d_in, const int* in_sizes, int n_in,
                              void* d_out, int out_size, void* d_ws, size_t ws_size,
                              hipStream_t stream)
{
    const float* score = (const float*)d_in[0];   // [B, N] fp32
    const float* roi   = (const float*)d_in[1];   // [B, N, 4] fp32
    float* out_roi   = (float*)d_out;                           // [B, K, 4]
    float* out_score = (float*)d_out + (size_t)BATCH * KSEL * 4; // [B, K]

    int* cnt  = (int*)d_ws;                       // [BATCH] counters
    ull* cand = (ull*)((char*)d_ws + 4096);       // [BATCH, cap] keys
    long long avail = ((long long)ws_size - 4096) / (long long)(sizeof(ull) * BATCH);
    int cap = (int)avail;
    if (cap > CAPMAX) cap = CAPMAX;
    if (cap < 1) cap = 1;

    hipMemsetAsync(cnt, 0, BATCH * sizeof(int), stream);
    topk_stage1<<<dim3(SPLITS, BATCH), TPB, 0, stream>>>(score, cand, cnt, cap);
    topk_stage2<<<BATCH, TPB, 0, stream>>>(cand, cnt, roi, out_roi, out_score, cap);
}